// Round 1
// baseline (49849.429 us; speedup 1.0000x reference)
//
#include <hip/hip_runtime.h>
#include <hip/hip_bf16.h>
#include <math.h>

#define DEV_INLINE __device__ __forceinline__

DEV_INLINE float wred_sum(float v) {
    #pragma unroll
    for (int o = 32; o > 0; o >>= 1) v += __shfl_xor(v, o);
    return v;
}
DEV_INLINE float wred_max(float v) {
    #pragma unroll
    for (int o = 32; o > 0; o >>= 1) v = fmaxf(v, __shfl_xor(v, o));
    return v;
}
DEV_INLINE float gelu_tanh(float v) {
    float t = tanhf(0.7978845608028654f * (v + 0.044715f * v * v * v));
    return 0.5f * v * (1.f + t);
}
DEV_INLINE float silu(float v) { return v / (1.f + expf(-v)); }

// ---------------------------------------------------------------------------
// Embedding gather: x[m,:] = embed[idx[m],:]   (float4 over D=768 -> 192 f4)
// ---------------------------------------------------------------------------
__global__ void embed_gather(const int* __restrict__ idx,
                             const float* __restrict__ embed,
                             float* __restrict__ x) {
    int i = blockIdx.x * blockDim.x + threadIdx.x;   // over 2048*192
    int m = i / 192, d4 = i % 192;
    ((float4*)x)[(size_t)m * 192 + d4] =
        ((const float4*)embed)[(size_t)idx[m] * 192 + d4];
}

// ---------------------------------------------------------------------------
// Timestep embedding: tf[b, i] = cos(sigma[b]*freq_i), tf[b,128+i] = sin(...)
// 1 block x 256 threads (B=2, half=128)
// ---------------------------------------------------------------------------
__global__ void tstep_embed(const float* __restrict__ sigma, float* __restrict__ tf) {
    int t = threadIdx.x;
    int b = t >> 7, i = t & 127;
    float freq = expf(-9.210340371976184f * (float)i / 128.f);  // ln(10000)
    float a = sigma[b] * freq;
    tf[b * 256 + i]       = cosf(a);
    tf[b * 256 + 128 + i] = sinf(a);
}

// ---------------------------------------------------------------------------
// Small-M GEMM: one wave per output element. out[m*N+n] = act(A[m,:].W[n,:]+b)
// ACT: 0 none, 2 silu
// ---------------------------------------------------------------------------
template <int ACT>
__global__ void gemm_rowvec(const float* __restrict__ A, const float* __restrict__ W,
                            const float* __restrict__ bias, float* __restrict__ C,
                            int M, int N, int K) {
    int wid  = (int)((blockIdx.x * (size_t)blockDim.x + threadIdx.x) >> 6);
    int lane = threadIdx.x & 63;
    if (wid >= M * N) return;
    int m = wid / N, n = wid % N;
    const float* a = A + (size_t)m * K;
    const float* w = W + (size_t)n * K;
    float s = 0.f;
    for (int k = lane; k < K; k += 64) s = fmaf(a[k], w[k], s);
    s = wred_sum(s);
    if (lane == 0) {
        if (bias) s += bias[n];
        if (ACT == 2) s = silu(s);
        C[wid] = s;
    }
}

// ---------------------------------------------------------------------------
// All adaLN modulations up-front: out[(l*B+b)*6D + j] = c[b,:].ada_w[l,j,:] + ada_b[l,j]
// ---------------------------------------------------------------------------
__global__ void ada_all(const float* __restrict__ c, const float* __restrict__ ada_w,
                        const float* __restrict__ ada_b, float* __restrict__ out) {
    const int C = 768, SIXD = 4608, B = 2, L = 12;
    int wid  = (int)((blockIdx.x * (size_t)blockDim.x + threadIdx.x) >> 6);
    int lane = threadIdx.x & 63;
    if (wid >= L * B * SIXD) return;
    int j = wid % SIXD;
    int lb = wid / SIXD;          // l*B + b
    int b = lb % B, l = lb / B;
    const float* a = c + (size_t)b * C;
    const float* w = ada_w + ((size_t)l * SIXD + j) * C;
    float s = 0.f;
    for (int k = lane; k < C; k += 64) s = fmaf(a[k], w[k], s);
    s = wred_sum(s);
    if (lane == 0) out[wid] = s + ada_b[l * SIXD + j];
}

// ---------------------------------------------------------------------------
// Modulated LayerNorm: out = LN(x)*w * (1+sc[b]) + sh[b], per row of D=768
// block = 256 threads, one block per row (r = b*S + s)
// ---------------------------------------------------------------------------
__global__ __launch_bounds__(256) void ln_mod(const float* __restrict__ x,
                                              const float* __restrict__ w,
                                              const float* __restrict__ sc,
                                              const float* __restrict__ sh,
                                              int bstride,
                                              float* __restrict__ out) {
    const int D = 768;
    int r = blockIdx.x;
    int b = r >> 10;  // S = 1024
    const float* xr = x + (size_t)r * D;
    int tid = threadIdx.x, lane = tid & 63, wv = tid >> 6;
    float v0 = xr[tid], v1 = xr[tid + 256], v2 = xr[tid + 512];
    __shared__ float redA[4], redB[4];
    float s = wred_sum(v0 + v1 + v2);
    if (lane == 0) redA[wv] = s;
    __syncthreads();
    float mu = (redA[0] + redA[1] + redA[2] + redA[3]) * (1.f / 768.f);
    float d0 = v0 - mu, d1 = v1 - mu, d2 = v2 - mu;
    float vs = wred_sum(d0 * d0 + d1 * d1 + d2 * d2);
    if (lane == 0) redB[wv] = vs;
    __syncthreads();
    float var  = (redB[0] + redB[1] + redB[2] + redB[3]) * (1.f / 768.f);
    float rstd = rsqrtf(var + 1e-5f);
    const float* scb = sc + (size_t)b * bstride;
    const float* shb = sh + (size_t)b * bstride;
    float* outr = out + (size_t)r * D;
    outr[tid]       = d0 * rstd * w[tid]       * (1.f + scb[tid])       + shb[tid];
    outr[tid + 256] = d1 * rstd * w[tid + 256] * (1.f + scb[tid + 256]) + shb[tid + 256];
    outr[tid + 512] = d2 * rstd * w[tid + 512] * (1.f + scb[tid + 512]) + shb[tid + 512];
}

// ---------------------------------------------------------------------------
// Gated residual: x[m,d] += g[b,d] * y[m,d]
// ---------------------------------------------------------------------------
__global__ void resid_gate(float* __restrict__ x, const float* __restrict__ y,
                           const float* __restrict__ g, int bstride) {
    int i = blockIdx.x * blockDim.x + threadIdx.x;  // M*D
    int d = i % 768;
    int m = i / 768;
    int b = m >> 10;
    x[i] += g[b * bstride + d] * y[i];
}

// ---------------------------------------------------------------------------
// Tiled fp32 GEMM: C[m,n] = act(sum_k A[m,k] * W[n,k] + bias[n])
// A: MxK row-major, W: NxK row-major (i.e. computes A @ W.T)
// BM=128, BN=64, BK=16; 256 threads; 8x4 micro-tile.
// M must be a multiple of 128. N, arbitrary (guarded). K multiple of 16.
// ACT: 0 none, 1 gelu
// ---------------------------------------------------------------------------
#define GBM 128
#define GBN 64
#define GBK 16
template <int ACT>
__global__ __launch_bounds__(256) void gemm_tn(const float* __restrict__ A,
                                               const float* __restrict__ W,
                                               const float* __restrict__ bias,
                                               float* __restrict__ C,
                                               int M, int N, int K) {
    __shared__ float As[GBK][GBM + 1];
    __shared__ float Ws[GBK][GBN + 1];
    int tid = threadIdx.x;
    int tx = tid & 15, ty = tid >> 4;
    int m0 = blockIdx.y * GBM, n0 = blockIdx.x * GBN;
    float acc[8][4] = {};
    for (int kk = 0; kk < K; kk += GBK) {
        // A tile: 128x16 = 2048 elems, 8 per thread
        #pragma unroll
        for (int e = 0; e < 8; e++) {
            int idx = tid * 8 + e;
            int am = idx >> 4, ak = idx & 15;
            As[ak][am] = A[(size_t)(m0 + am) * K + kk + ak];
        }
        // W tile: 64x16 = 1024 elems, 4 per thread (guard N)
        #pragma unroll
        for (int e = 0; e < 4; e++) {
            int idx = tid * 4 + e;
            int wn = idx >> 4, wk = idx & 15;
            float wv = 0.f;
            if (n0 + wn < N) wv = W[(size_t)(n0 + wn) * K + kk + wk];
            Ws[wk][wn] = wv;
        }
        __syncthreads();
        #pragma unroll
        for (int k = 0; k < GBK; k++) {
            float a[8], b[4];
            #pragma unroll
            for (int i = 0; i < 8; i++) a[i] = As[k][ty * 8 + i];
            #pragma unroll
            for (int j = 0; j < 4; j++) b[j] = Ws[k][tx * 4 + j];
            #pragma unroll
            for (int i = 0; i < 8; i++)
                #pragma unroll
                for (int j = 0; j < 4; j++)
                    acc[i][j] = fmaf(a[i], b[j], acc[i][j]);
        }
        __syncthreads();
    }
    #pragma unroll
    for (int i = 0; i < 8; i++) {
        int m = m0 + ty * 8 + i;
        #pragma unroll
        for (int j = 0; j < 4; j++) {
            int n = n0 + tx * 4 + j;
            if (n < N) {
                float v = acc[i][j];
                if (bias) v += bias[n];
                if (ACT == 1) v = gelu_tanh(v);
                C[(size_t)m * N + n] = v;
            }
        }
    }
}

// ---------------------------------------------------------------------------
// Attention: one block per (b, h, 8-query tile). S=1024, dh=64, H=12.
// qkv row layout: [3, H, dh] -> q at h*64, k at 768+h*64, v at 1536+h*64
// ---------------------------------------------------------------------------
__global__ __launch_bounds__(256) void attn_kernel(const float* __restrict__ qkv,
                                                   float* __restrict__ o) {
    const int S = 1024, H = 12, C3 = 2304;
    const float scale = 0.125f;  // 1/sqrt(64)
    int bid = blockIdx.x;
    int qt = bid & 127;
    int bh = bid >> 7;
    int h = bh % H, b = bh / H;
    int q0 = qt * 8;
    int tid = threadIdx.x;

    __shared__ __align__(16) float qs[8][64];
    __shared__ float scb[8][1024];
    __shared__ float part[4][8][64];
    __shared__ float wredA[4], wredB[4];

    // load Q tile (512 floats)
    #pragma unroll
    for (int e = 0; e < 2; e++) {
        int i = tid + e * 256;
        int q = i >> 6, d = i & 63;
        qs[q][d] = qkv[(size_t)(b * S + q0 + q) * C3 + h * 64 + d];
    }
    __syncthreads();

    // scores: each thread handles 4 keys, caches K row in registers
    #pragma unroll
    for (int ki = 0; ki < 4; ki++) {
        int k = ki * 256 + tid;
        const float* kp = qkv + (size_t)(b * S + k) * C3 + 768 + h * 64;
        float4 kr[16];
        #pragma unroll
        for (int j = 0; j < 16; j++) kr[j] = ((const float4*)kp)[j];
        #pragma unroll
        for (int q = 0; q < 8; q++) {
            const float4* qv = (const float4*)qs[q];
            float d = 0.f;
            #pragma unroll
            for (int j = 0; j < 16; j++) {
                float4 a = qv[j];
                d += a.x * kr[j].x + a.y * kr[j].y + a.z * kr[j].z + a.w * kr[j].w;
            }
            scb[q][k] = d * scale;
        }
    }
    __syncthreads();

    // softmax per query row
    int lane = tid & 63, wv = tid >> 6;
    for (int q = 0; q < 8; q++) {
        float m = -1e30f;
        #pragma unroll
        for (int ki = 0; ki < 4; ki++) m = fmaxf(m, scb[q][ki * 256 + tid]);
        m = wred_max(m);
        if (lane == 0) wredA[wv] = m;
        __syncthreads();
        m = fmaxf(fmaxf(wredA[0], wredA[1]), fmaxf(wredA[2], wredA[3]));
        float s = 0.f;
        #pragma unroll
        for (int ki = 0; ki < 4; ki++) {
            int k = ki * 256 + tid;
            float e = expf(scb[q][k] - m);
            scb[q][k] = e;
            s += e;
        }
        s = wred_sum(s);
        if (lane == 0) wredB[wv] = s;
        __syncthreads();
        float inv = 1.f / (wredB[0] + wredB[1] + wredB[2] + wredB[3]);
        #pragma unroll
        for (int ki = 0; ki < 4; ki++) scb[q][ki * 256 + tid] *= inv;
    }
    __syncthreads();

    // output: o[q,d] = sum_k p[q,k] * V[k,d]; thread = (kc, d)
    {
        int d = tid & 63, kc = tid >> 6;
        float acc[8] = {};
        for (int kk = 0; kk < 256; kk++) {
            int k = kc * 256 + kk;
            float v = qkv[(size_t)(b * S + k) * C3 + 1536 + h * 64 + d];
            #pragma unroll
            for (int q = 0; q < 8; q++) acc[q] = fmaf(scb[q][k], v, acc[q]);
        }
        #pragma unroll
        for (int q = 0; q < 8; q++) part[kc][q][d] = acc[q];
        __syncthreads();
        #pragma unroll
        for (int p = 0; p < 2; p++) {
            int q = p * 4 + (tid >> 6);
            float s = part[0][q][d] + part[1][q][d] + part[2][q][d] + part[3][q][d];
            o[(size_t)(b * S + q0 + q) * 768 + h * 64 + d] = s;
        }
    }
}

// ---------------------------------------------------------------------------
// Host orchestration
// ---------------------------------------------------------------------------
extern "C" void kernel_launch(void* const* d_in, const int* in_sizes, int n_in,
                              void* d_out, int out_size, void* d_ws, size_t ws_size,
                              hipStream_t stream) {
    const int B = 2, S = 1024, D = 768, H = 12, L = 12, V = 50258, C = 768, F = 256,
              MLP = 3072;
    const int M = B * S;

    const int*   indices = (const int*)d_in[0];
    const float* sigma   = (const float*)d_in[1];
    const float* embed   = (const float*)d_in[2];
    const float* t_w1    = (const float*)d_in[3];
    const float* t_b1    = (const float*)d_in[4];
    const float* t_w2    = (const float*)d_in[5];
    const float* t_b2    = (const float*)d_in[6];
    const float* norm1_w = (const float*)d_in[7];
    const float* qkv_w   = (const float*)d_in[8];
    const float* out_w   = (const float*)d_in[9];
    const float* norm2_w = (const float*)d_in[10];
    const float* mlp_w1  = (const float*)d_in[11];
    const float* mlp_b1  = (const float*)d_in[12];
    const float* mlp_w2  = (const float*)d_in[13];
    const float* mlp_b2  = (const float*)d_in[14];
    const float* ada_w   = (const float*)d_in[15];
    const float* ada_b   = (const float*)d_in[16];
    const float* normf_w = (const float*)d_in[17];
    const float* lin_w   = (const float*)d_in[18];
    const float* lin_b   = (const float*)d_in[19];
    const float* adaf_w  = (const float*)d_in[20];
    const float* adaf_b  = (const float*)d_in[21];

    float* ws = (float*)d_ws;
    float* x    = ws;  ws += (size_t)M * D;
    float* xm   = ws;  ws += (size_t)M * D;
    float* qkv  = ws;  ws += (size_t)M * 3 * D;
    float* ao   = ws;  ws += (size_t)M * D;
    float* yb   = ws;  ws += (size_t)M * D;
    float* hb   = ws;  ws += (size_t)M * MLP;
    float* tf   = ws;  ws += (size_t)B * F;
    float* h1   = ws;  ws += (size_t)B * C;
    float* cb   = ws;  ws += (size_t)B * C;
    float* ada  = ws;  ws += (size_t)L * B * 6 * D;
    float* adaf = ws;  ws += (size_t)B * 2 * D;

    // x = embed[indices]
    embed_gather<<<(M * 192) / 256, 256, 0, stream>>>(indices, embed, x);
    // timestep embedding + MLP -> c = silu(temb)
    tstep_embed<<<1, 256, 0, stream>>>(sigma, tf);
    gemm_rowvec<2><<<(B * C * 64) / 256, 256, 0, stream>>>(tf, t_w1, t_b1, h1, B, C, F);
    gemm_rowvec<2><<<(B * C * 64) / 256, 256, 0, stream>>>(h1, t_w2, t_b2, cb, B, C, C);
    // all adaLN modulations
    ada_all<<<(L * B * 6 * D * 64) / 256, 256, 0, stream>>>(cb, ada_w, ada_b, ada);
    gemm_rowvec<0><<<(B * 2 * D * 64) / 256, 256, 0, stream>>>(cb, adaf_w, adaf_b, adaf,
                                                               B, 2 * D, C);

    dim3 blk(256);
    for (int l = 0; l < L; l++) {
        const float* adaL = ada + (size_t)l * B * 6 * D;
        // xm = LN(x, norm1)*(1+sc_msa) + sh_msa
        ln_mod<<<M, blk, 0, stream>>>(x, norm1_w + (size_t)l * D, adaL + D, adaL,
                                      6 * D, xm);
        // qkv = xm @ qkv_w[l].T
        gemm_tn<0><<<dim3((3 * D) / GBN, M / GBM), blk, 0, stream>>>(
            xm, qkv_w + (size_t)l * 3 * D * D, nullptr, qkv, M, 3 * D, D);
        // attention
        attn_kernel<<<B * H * (S / 8), blk, 0, stream>>>(qkv, ao);
        // y = o @ out_w[l].T ; x += g_msa * y
        gemm_tn<0><<<dim3(D / GBN, M / GBM), blk, 0, stream>>>(
            ao, out_w + (size_t)l * D * D, nullptr, yb, M, D, D);
        resid_gate<<<(M * D) / 256, blk, 0, stream>>>(x, yb, adaL + 2 * D, 6 * D);
        // xm = LN(x, norm2)*(1+sc_mlp) + sh_mlp
        ln_mod<<<M, blk, 0, stream>>>(x, norm2_w + (size_t)l * D, adaL + 4 * D,
                                      adaL + 3 * D, 6 * D, xm);
        // h = gelu(xm @ mlp_w1.T + b1); y = h @ mlp_w2.T + b2; x += g_mlp * y
        gemm_tn<1><<<dim3(MLP / GBN, M / GBM), blk, 0, stream>>>(
            xm, mlp_w1 + (size_t)l * MLP * D, mlp_b1 + (size_t)l * MLP, hb, M, MLP, D);
        gemm_tn<0><<<dim3(D / GBN, M / GBM), blk, 0, stream>>>(
            hb, mlp_w2 + (size_t)l * D * MLP, mlp_b2 + (size_t)l * D, yb, M, D, MLP);
        resid_gate<<<(M * D) / 256, blk, 0, stream>>>(x, yb, adaL + 5 * D, 6 * D);
    }

    // final: xm = LN(x, normf)*(1+sc)+shift ; out = xm @ lin_w.T + lin_b
    ln_mod<<<M, blk, 0, stream>>>(x, normf_w, adaf + D, adaf, 2 * D, xm);
    gemm_tn<0><<<dim3((V + GBN - 1) / GBN, M / GBM), blk, 0, stream>>>(
        xm, lin_w, lin_b, (float*)d_out, M, V, D);
}

// Round 3
// 3109.315 us; speedup vs baseline: 16.0323x; 16.0323x over previous
//
#include <hip/hip_runtime.h>
#include <hip/hip_bf16.h>
#include <math.h>
#include <stdint.h>

typedef __hip_bfloat16 bf16;
typedef __attribute__((ext_vector_type(8))) short bf16x8;   // 8 bf16 = 4 VGPR
typedef __attribute__((ext_vector_type(4))) float f32x4;

#define DEV_INLINE __device__ __forceinline__

DEV_INLINE float wred_sum(float v) {
    #pragma unroll
    for (int o = 32; o > 0; o >>= 1) v += __shfl_xor(v, o);
    return v;
}
DEV_INLINE float red16_max(float v) {
    v = fmaxf(v, __shfl_xor(v, 1)); v = fmaxf(v, __shfl_xor(v, 2));
    v = fmaxf(v, __shfl_xor(v, 4)); v = fmaxf(v, __shfl_xor(v, 8));
    return v;
}
DEV_INLINE float red16_sum(float v) {
    v += __shfl_xor(v, 1); v += __shfl_xor(v, 2);
    v += __shfl_xor(v, 4); v += __shfl_xor(v, 8);
    return v;
}
DEV_INLINE float gelu_tanh(float v) {
    float t = tanhf(0.7978845608028654f * (v + 0.044715f * v * v * v));
    return 0.5f * v * (1.f + t);
}
DEV_INLINE float silu(float v) { return v / (1.f + expf(-v)); }
DEV_INLINE short f2bs(float f) { bf16 h = __float2bfloat16(f); short s; __builtin_memcpy(&s, &h, 2); return s; }

typedef const __attribute__((address_space(1))) uint32_t* gptr_t;
typedef __attribute__((address_space(3))) uint32_t* lptr_t;

// global -> LDS direct copy, 16B per lane; LDS dest = wave-uniform base + lane*16
DEV_INLINE void gload_lds16(const bf16* gp, bf16* lp) {
    __builtin_amdgcn_global_load_lds((gptr_t)gp, (lptr_t)lp, 16, 0, 0);
}

// ---------------------------------------------------------------------------
// fp32 -> bf16 conversion, 8 elems/thread, n multiple of 8
// ---------------------------------------------------------------------------
__global__ void cvt_bf16(const float* __restrict__ in, bf16* __restrict__ out, long n) {
    long i = ((long)blockIdx.x * blockDim.x + threadIdx.x) * 8;
    if (i >= n) return;
    float4 a = *(const float4*)(in + i);
    float4 b = *(const float4*)(in + i + 4);
    bf16x8 v;
    v[0] = f2bs(a.x); v[1] = f2bs(a.y); v[2] = f2bs(a.z); v[3] = f2bs(a.w);
    v[4] = f2bs(b.x); v[5] = f2bs(b.y); v[6] = f2bs(b.z); v[7] = f2bs(b.w);
    *(bf16x8*)(out + i) = v;
}

// ---------------------------------------------------------------------------
// Embedding gather (fp32 residual stream)
// ---------------------------------------------------------------------------
__global__ void embed_gather(const int* __restrict__ idx,
                             const float* __restrict__ embed,
                             float* __restrict__ x) {
    int i = blockIdx.x * blockDim.x + threadIdx.x;   // 2048*192
    int m = i / 192, d4 = i % 192;
    ((float4*)x)[(size_t)m * 192 + d4] =
        ((const float4*)embed)[(size_t)idx[m] * 192 + d4];
}

// ---------------------------------------------------------------------------
// Timestep embedding
// ---------------------------------------------------------------------------
__global__ void tstep_embed(const float* __restrict__ sigma, float* __restrict__ tf) {
    int t = threadIdx.x;
    int b = t >> 7, i = t & 127;
    float freq = expf(-9.210340371976184f * (float)i / 128.f);
    float a = sigma[b] * freq;
    tf[b * 256 + i]       = cosf(a);
    tf[b * 256 + 128 + i] = sinf(a);
}

// ---------------------------------------------------------------------------
// Small-M GEMM (fp32): one wave per output element. ACT: 0 none, 2 silu
// ---------------------------------------------------------------------------
template <int ACT>
__global__ void gemm_rowvec(const float* __restrict__ A, const float* __restrict__ W,
                            const float* __restrict__ bias, float* __restrict__ C,
                            int M, int N, int K) {
    int wid  = (int)((blockIdx.x * (size_t)blockDim.x + threadIdx.x) >> 6);
    int lane = threadIdx.x & 63;
    if (wid >= M * N) return;
    int m = wid / N, n = wid % N;
    const float* a = A + (size_t)m * K;
    const float* w = W + (size_t)n * K;
    float s = 0.f;
    for (int k = lane; k < K; k += 64) s = fmaf(a[k], w[k], s);
    s = wred_sum(s);
    if (lane == 0) {
        if (bias) s += bias[n];
        if (ACT == 2) s = silu(s);
        C[wid] = s;
    }
}

// ---------------------------------------------------------------------------
// All adaLN modulations (fp32, M=2 — memory-bound on ada_w)
// ---------------------------------------------------------------------------
__global__ void ada_all(const float* __restrict__ c, const float* __restrict__ ada_w,
                        const float* __restrict__ ada_b, float* __restrict__ out) {
    const int C = 768, SIXD = 4608, B = 2;
    int wid  = (int)((blockIdx.x * (size_t)blockDim.x + threadIdx.x) >> 6);
    int lane = threadIdx.x & 63;
    if (wid >= 12 * B * SIXD) return;
    int j = wid % SIXD;
    int lb = wid / SIXD;
    int b = lb % B, l = lb / B;
    const float* a = c + (size_t)b * C;
    const float* w = ada_w + ((size_t)l * SIXD + j) * C;
    float s = 0.f;
    for (int k = lane; k < C; k += 64) s = fmaf(a[k], w[k], s);
    s = wred_sum(s);
    if (lane == 0) out[wid] = s + ada_b[l * SIXD + j];
}

// ---------------------------------------------------------------------------
// Modulated LayerNorm, fp32 in -> bf16 out
// ---------------------------------------------------------------------------
__global__ __launch_bounds__(256) void ln_mod(const float* __restrict__ x,
                                              const float* __restrict__ w,
                                              const float* __restrict__ sc,
                                              const float* __restrict__ sh,
                                              int bstride,
                                              bf16* __restrict__ out) {
    int r = blockIdx.x;
    int b = r >> 10;
    const float* xr = x + (size_t)r * 768;
    int tid = threadIdx.x, lane = tid & 63, wv = tid >> 6;
    float v0 = xr[tid], v1 = xr[tid + 256], v2 = xr[tid + 512];
    __shared__ float redA[4], redB[4];
    float s = wred_sum(v0 + v1 + v2);
    if (lane == 0) redA[wv] = s;
    __syncthreads();
    float mu = (redA[0] + redA[1] + redA[2] + redA[3]) * (1.f / 768.f);
    float d0 = v0 - mu, d1 = v1 - mu, d2 = v2 - mu;
    float vs = wred_sum(d0 * d0 + d1 * d1 + d2 * d2);
    if (lane == 0) redB[wv] = vs;
    __syncthreads();
    float var  = (redB[0] + redB[1] + redB[2] + redB[3]) * (1.f / 768.f);
    float rstd = rsqrtf(var + 1e-5f);
    const float* scb = sc + (size_t)b * bstride;
    const float* shb = sh + (size_t)b * bstride;
    bf16* outr = out + (size_t)r * 768;
    outr[tid]       = __float2bfloat16(d0 * rstd * w[tid]       * (1.f + scb[tid])       + shb[tid]);
    outr[tid + 256] = __float2bfloat16(d1 * rstd * w[tid + 256] * (1.f + scb[tid + 256]) + shb[tid + 256]);
    outr[tid + 512] = __float2bfloat16(d2 * rstd * w[tid + 512] * (1.f + scb[tid + 512]) + shb[tid + 512]);
}

// ---------------------------------------------------------------------------
// Gated residual: x[m,d] += g[b,d] * y[m,d]   (fp32)
// ---------------------------------------------------------------------------
__global__ void resid_gate(float* __restrict__ x, const float* __restrict__ y,
                           const float* __restrict__ g, int bstride) {
    int i = blockIdx.x * blockDim.x + threadIdx.x;
    int d = i % 768;
    int b = (i / 768) >> 10;
    x[i] += g[b * bstride + d] * y[i];
}

// ---------------------------------------------------------------------------
// bf16 MFMA GEMM (m97 structure): C = act(A @ W^T + bias)
// A: MxK bf16 row-major; W: NxK bf16 row-major. Tile 128x128, BK=32.
// 256 thr = 4 waves; wave (w>>1, w&1) owns a 64x64 sub-tile (4x4 fragments).
// M % 128 == 0, K % 32 == 0, N arbitrary (W rows clamped, C cols guarded).
// ACT: 0 none, 1 gelu.  OBF: 1 -> bf16 out, 0 -> fp32 out.
// ---------------------------------------------------------------------------
template <int ACT, int OBF>
__global__ __launch_bounds__(256) void gemm_mfma(const bf16* __restrict__ A,
                                                 const bf16* __restrict__ W,
                                                 const float* __restrict__ bias,
                                                 void* __restrict__ Cout,
                                                 int M, int N, int K) {
    __shared__ __align__(16) bf16 As[128 * 32];
    __shared__ __align__(16) bf16 Ws[128 * 32];
    int tid = threadIdx.x;
    int w = tid >> 6, l = tid & 63;
    int l16 = l & 15, g = l >> 4;
    int m0 = blockIdx.y * 128, n0 = blockIdx.x * 128;
    int wr = (w >> 1) * 64, wc = (w & 1) * 64;

    f32x4 acc[4][4];
    f32x4 zero4 = {0.f, 0.f, 0.f, 0.f};
    #pragma unroll
    for (int i = 0; i < 4; i++)
        #pragma unroll
        for (int j = 0; j < 4; j++) acc[i][j] = zero4;

    // staging: wave w covers tile rows [w*32, w*32+32), 2 issues of 16 rows
    int srow = w * 32 + (l >> 2);        // + e*16
    int scol = (l & 3) * 8;
    const bf16* gA0 = A + (size_t)(m0 + srow) * K + scol;
    const bf16* gA1 = gA0 + (size_t)16 * K;
    int nr0 = n0 + srow;      if (nr0 > N - 1) nr0 = N - 1;
    int nr1 = n0 + srow + 16; if (nr1 > N - 1) nr1 = N - 1;
    const bf16* gW0 = W + (size_t)nr0 * K + scol;
    const bf16* gW1 = W + (size_t)nr1 * K + scol;
    bf16* lA0 = &As[(w * 32) * 32];
    bf16* lA1 = &As[(w * 32 + 16) * 32];
    bf16* lW0 = &Ws[(w * 32) * 32];
    bf16* lW1 = &Ws[(w * 32 + 16) * 32];

    for (int kk = 0; kk < K; kk += 32) {
        __syncthreads();
        gload_lds16(gA0 + kk, lA0);
        gload_lds16(gA1 + kk, lA1);
        gload_lds16(gW0 + kk, lW0);
        gload_lds16(gW1 + kk, lW1);
        __syncthreads();
        bf16x8 af[4], bfr[4];
        #pragma unroll
        for (int mi = 0; mi < 4; mi++)
            af[mi] = *(const bf16x8*)&As[(wr + mi * 16 + l16) * 32 + g * 8];
        #pragma unroll
        for (int ni = 0; ni < 4; ni++)
            bfr[ni] = *(const bf16x8*)&Ws[(wc + ni * 16 + l16) * 32 + g * 8];
        #pragma unroll
        for (int mi = 0; mi < 4; mi++)
            #pragma unroll
            for (int ni = 0; ni < 4; ni++)
                acc[mi][ni] = __builtin_amdgcn_mfma_f32_16x16x32_bf16(
                    af[mi], bfr[ni], acc[mi][ni], 0, 0, 0);
    }

    // epilogue: C/D layout col = lane&15, row = (lane>>4)*4 + reg  [m89]
    #pragma unroll
    for (int ni = 0; ni < 4; ni++) {
        int col = n0 + wc + ni * 16 + l16;
        if (col >= N) continue;
        float bv = bias ? bias[col] : 0.f;
        #pragma unroll
        for (int mi = 0; mi < 4; mi++) {
            #pragma unroll
            for (int jj = 0; jj < 4; jj++) {
                int row = m0 + wr + mi * 16 + g * 4 + jj;
                float v = acc[mi][ni][jj] + bv;
                if (ACT == 1) v = gelu_tanh(v);
                if (OBF) ((bf16*)Cout)[(size_t)row * N + col] = __float2bfloat16(v);
                else     ((float*)Cout)[(size_t)row * N + col] = v;
            }
        }
    }
}

// ---------------------------------------------------------------------------
// V repack: qkv[m, 1536 + h*64 + d] -> vt[bh, d, s]  (transpose per head)
// grid: (16 key-tiles, 24 bh), 256 threads
// ---------------------------------------------------------------------------
__global__ __launch_bounds__(256) void repack_vt(const bf16* __restrict__ qkv,
                                                 bf16* __restrict__ vt) {
    int bh = blockIdx.y, b = bh / 12, h = bh % 12;
    int k0 = blockIdx.x * 64;
    __shared__ __align__(16) bf16 t[64][72];
    int tid = threadIdx.x;
    #pragma unroll
    for (int e = 0; e < 2; e++) {
        int idx = tid + e * 256;
        int ky = idx >> 3, dc = (idx & 7) * 8;
        bf16x8 v = *(const bf16x8*)&qkv[(size_t)(b * 1024 + k0 + ky) * 2304 + 1536 + h * 64 + dc];
        *(bf16x8*)&t[ky][dc] = v;
    }
    __syncthreads();
    #pragma unroll
    for (int e = 0; e < 2; e++) {
        int idx = tid + e * 256;
        int d = idx >> 3, kc = (idx & 7) * 8;
        bf16x8 o;
        #pragma unroll
        for (int j = 0; j < 8; j++) { bf16 hv = t[kc + j][d]; short s; __builtin_memcpy(&s, &hv, 2); o[j] = s; }
        *(bf16x8*)&vt[((size_t)bh * 64 + d) * 1024 + k0 + kc] = o;
    }
}

// ---------------------------------------------------------------------------
// Flash attention, bf16 MFMA. grid: (16 q-tiles, 24 bh), 256 thr = 4 waves.
// Q tile 64 rows (16/wave, in regs). Per KV step (64 keys): stage K and V^T
// tiles in LDS (XOR-swizzled rows), QK^T -> online softmax (reg) -> P via
// per-wave LDS transpose -> PV. K/V^T rows are 128B: swizzle byte^=((r&7)<<4).
// ---------------------------------------------------------------------------
__global__ __launch_bounds__(256) void attn_mfma(const bf16* __restrict__ qkv,
                                                 const bf16* __restrict__ vt,
                                                 bf16* __restrict__ ao) {
    const int S = 1024, C3 = 2304;
    int bh = blockIdx.y, b = bh / 12, h = bh % 12;
    int q0 = blockIdx.x * 64;
    int tid = threadIdx.x, w = tid >> 6, l = tid & 63;
    int l16 = l & 15, g = l >> 4;

    __shared__ __align__(16) bf16 Ks[64 * 64];
    __shared__ __align__(16) bf16 Vs[64 * 64];   // [d][key], swizzled
    __shared__ __align__(16) bf16 Ps[4][16 * 72];

    // Q fragments (A-layout): lane holds Q[q0+w*16+l16][kc*32 + g*8 .. +8]
    const size_t qbase = ((size_t)(b * S + q0 + w * 16 + l16)) * C3 + h * 64;
    bf16x8 qf[2];
    qf[0] = *(const bf16x8*)&qkv[qbase + g * 8];
    qf[1] = *(const bf16x8*)&qkv[qbase + 32 + g * 8];

    f32x4 o_acc[4];
    f32x4 zero4 = {0.f, 0.f, 0.f, 0.f};
    #pragma unroll
    for (int ni = 0; ni < 4; ni++) o_acc[ni] = zero4;
    float mrow[4] = {-1e30f, -1e30f, -1e30f, -1e30f};
    float lrow[4] = {0.f, 0.f, 0.f, 0.f};
    const float cscale = 0.125f * 1.44269504088896f;   // log2(e)/sqrt(dh)

    // staging addresses (pre-swizzled global source, linear LDS dest)
    int sr0 = w * 16 + (l >> 3);          // tile row, issue 0
    int sr1 = sr0 + 8;                    // issue 1
    int cb  = (l & 7) * 16;               // LDS byte col within 128B row
    int sc0 = (cb ^ ((sr0 & 7) << 4)) >> 1;   // source elem col
    int sc1 = (cb ^ ((sr1 & 7) << 4)) >> 1;
    const bf16* gk0 = qkv + ((size_t)(b * S) + sr0) * C3 + 768 + h * 64 + sc0;
    const bf16* gk1 = qkv + ((size_t)(b * S) + sr1) * C3 + 768 + h * 64 + sc1;
    const bf16* gv0 = vt + ((size_t)bh * 64 + sr0) * 1024 + sc0;
    const bf16* gv1 = vt + ((size_t)bh * 64 + sr1) * 1024 + sc1;
    bf16* lk0 = &Ks[(w * 16) * 64];
    bf16* lk1 = &Ks[(w * 16 + 8) * 64];
    bf16* lv0 = &Vs[(w * 16) * 64];
    bf16* lv1 = &Vs[(w * 16 + 8) * 64];

    for (int kv0 = 0; kv0 < S; kv0 += 64) {
        __syncthreads();
        gload_lds16(gk0 + (size_t)kv0 * C3, lk0);
        gload_lds16(gk1 + (size_t)kv0 * C3, lk1);
        gload_lds16(gv0 + kv0, lv0);
        gload_lds16(gv1 + kv0, lv1);
        __syncthreads();

        // QK^T: S[q = g*4+jj][key = kf*16+l16]
        f32x4 sfrag[4];
        #pragma unroll
        for (int kf = 0; kf < 4; kf++) {
            sfrag[kf] = zero4;
            int key = kf * 16 + l16;
            #pragma unroll
            for (int kc = 0; kc < 2; kc++) {
                int byteoff = key * 128 + (((kc * 32 + g * 8) * 2) ^ ((key & 7) << 4));
                bf16x8 kb = *(const bf16x8*)((const char*)Ks + byteoff);
                sfrag[kf] = __builtin_amdgcn_mfma_f32_16x16x32_bf16(qf[kc], kb, sfrag[kf], 0, 0, 0);
            }
        }

        // online softmax (per q-row j; 16-lane group shares the row)
        float pv[4][4];
        #pragma unroll
        for (int j = 0; j < 4; j++) {
            float t0 = sfrag[0][j] * cscale, t1 = sfrag[1][j] * cscale;
            float t2 = sfrag[2][j] * cscale, t3 = sfrag[3][j] * cscale;
            float mx = fmaxf(fmaxf(t0, t1), fmaxf(t2, t3));
            mx = red16_max(mx);
            float mnew = fmaxf(mrow[j], mx);
            float r = exp2f(mrow[j] - mnew);
            mrow[j] = mnew;
            float p0 = exp2f(t0 - mnew), p1 = exp2f(t1 - mnew);
            float p2 = exp2f(t2 - mnew), p3 = exp2f(t3 - mnew);
            pv[0][j] = p0; pv[1][j] = p1; pv[2][j] = p2; pv[3][j] = p3;
            float ps = red16_sum(p0 + p1 + p2 + p3);
            lrow[j] = lrow[j] * r + ps;
            #pragma unroll
            for (int ni = 0; ni < 4; ni++) o_acc[ni][j] *= r;
        }

        // P: C-layout -> A-layout via per-wave LDS (row stride 72 elems)
        #pragma unroll
        for (int kf = 0; kf < 4; kf++)
            #pragma unroll
            for (int j = 0; j < 4; j++)
                Ps[w][(g * 4 + j) * 72 + kf * 16 + l16] = __float2bfloat16(pv[kf][j]);
        __syncthreads();

        // PV: O[q][d] += P[q][key] @ V[key][d]
        #pragma unroll
        for (int kc = 0; kc < 2; kc++) {
            bf16x8 pa = *(const bf16x8*)&Ps[w][l16 * 72 + kc * 32 + g * 8];
            #pragma unroll
            for (int ni = 0; ni < 4; ni++) {
                int d = ni * 16 + l16;
                int byteoff = d * 128 + (((kc * 32 + g * 8) * 2) ^ ((d & 7) << 4));
                bf16x8 vb = *(const bf16x8*)((const char*)Vs + byteoff);
                o_acc[ni] = __builtin_amdgcn_mfma_f32_16x16x32_bf16(pa, vb, o_acc[ni], 0, 0, 0);
            }
        }
    }

    // normalize and write: row q = q0 + w*16 + g*4 + jj, col = h*64 + ni*16 + l16
    float linv[4];
    #pragma unroll
    for (int j = 0; j < 4; j++) linv[j] = 1.f / lrow[j];
    #pragma unroll
    for (int ni = 0; ni < 4; ni++) {
        #pragma unroll
        for (int jj = 0; jj < 4; jj++) {
            int row = q0 + w * 16 + g * 4 + jj;
            ao[((size_t)(b * S + row)) * 768 + h * 64 + ni * 16 + l16] =
                __float2bfloat16(o_acc[ni][jj] * linv[jj]);
        }
    }
}

// ---------------------------------------------------------------------------
// Host orchestration
// ---------------------------------------------------------------------------
extern "C" void kernel_launch(void* const* d_in, const int* in_sizes, int n_in,
                              void* d_out, int out_size, void* d_ws, size_t ws_size,
                              hipStream_t stream) {
    const int B = 2, S = 1024, D = 768, L = 12, V = 50258, C = 768, F = 256, MLP = 3072;
    const int M = B * S;

    const int*   indices = (const int*)d_in[0];
    const float* sigma   = (const float*)d_in[1];
    const float* embed   = (const float*)d_in[2];
    const float* t_w1    = (const float*)d_in[3];
    const float* t_b1    = (const float*)d_in[4];
    const float* t_w2    = (const float*)d_in[5];
    const float* t_b2    = (const float*)d_in[6];
    const float* norm1_w = (const float*)d_in[7];
    const float* qkv_w   = (const float*)d_in[8];
    const float* out_w   = (const float*)d_in[9];
    const float* norm2_w = (const float*)d_in[10];
    const float* mlp_w1  = (const float*)d_in[11];
    const float* mlp_b1  = (const float*)d_in[12];
    const float* mlp_w2  = (const float*)d_in[13];
    const float* mlp_b2  = (const float*)d_in[14];
    const float* ada_w   = (const float*)d_in[15];
    const float* ada_b   = (const float*)d_in[16];
    const float* normf_w = (const float*)d_in[17];
    const float* lin_w   = (const float*)d_in[18];
    const float* lin_b   = (const float*)d_in[19];
    const float* adaf_w  = (const float*)d_in[20];
    const float* adaf_b  = (const float*)d_in[21];

    char* p = (char*)d_ws;
    auto alloc = [&](size_t bytes) { char* r = p; p += (bytes + 255) & ~(size_t)255; return r; };

    float* x    = (float*)alloc((size_t)M * D * 4);
    float* yb   = (float*)alloc((size_t)M * D * 4);
    bf16*  xm   = (bf16*) alloc((size_t)M * D * 2);
    bf16*  qkvb = (bf16*) alloc((size_t)M * 3 * D * 2);
    bf16*  aob  = (bf16*) alloc((size_t)M * D * 2);
    bf16*  hbb  = (bf16*) alloc((size_t)M * MLP * 2);
    bf16*  vtb  = (bf16*) alloc((size_t)24 * 64 * 1024 * 2);
    bf16*  wl   = (bf16*) alloc((size_t)(2304*768 + 768*768 + 3072*768 + 768*3072) * 2);
    bf16*  linb = (bf16*) alloc((size_t)V * D * 2);
    float* tf   = (float*)alloc((size_t)B * F * 4);
    float* h1   = (float*)alloc((size_t)B * C * 4);
    float* cb   = (float*)alloc((size_t)B * C * 4);
    float* ada  = (float*)alloc((size_t)L * B * 6 * D * 4);
    float* adaf = (float*)alloc((size_t)B * 2 * D * 4);

    const size_t off_qkvw = 0;
    const size_t off_outw = (size_t)2304 * 768;
    const size_t off_w1   = off_outw + (size_t)768 * 768;
    const size_t off_w2   = off_w1 + (size_t)3072 * 768;

    auto cgrid = [](long n) { return (unsigned)((n / 8 + 255) / 256); };
    dim3 blk(256);

    // prologue
    embed_gather<<<(M * 192) / 256, blk, 0, stream>>>(indices, embed, x);
    tstep_embed<<<1, blk, 0, stream>>>(sigma, tf);
    gemm_rowvec<2><<<(B * C * 64) / 256, blk, 0, stream>>>(tf, t_w1, t_b1, h1, B, C, F);
    gemm_rowvec<2><<<(B * C * 64) / 256, blk, 0, stream>>>(h1, t_w2, t_b2, cb, B, C, C);
    ada_all<<<(L * B * 6 * D * 64) / 256, blk, 0, stream>>>(cb, ada_w, ada_b, ada);
    gemm_rowvec<0><<<(B * 2 * D * 64) / 256, blk, 0, stream>>>(cb, adaf_w, adaf_b, adaf, B, 2 * D, C);
    cvt_bf16<<<cgrid((long)V * D), blk, 0, stream>>>(lin_w, linb, (long)V * D);

    for (int l = 0; l < L; l++) {
        const float* adaL = ada + (size_t)l * B * 6 * D;
        // per-layer weight conversion
        cvt_bf16<<<cgrid((long)2304 * 768), blk, 0, stream>>>(qkv_w + (size_t)l * 2304 * 768, wl + off_qkvw, (long)2304 * 768);
        cvt_bf16<<<cgrid((long)768 * 768),  blk, 0, stream>>>(out_w + (size_t)l * 768 * 768,  wl + off_outw, (long)768 * 768);
        cvt_bf16<<<cgrid((long)3072 * 768), blk, 0, stream>>>(mlp_w1 + (size_t)l * 3072 * 768, wl + off_w1, (long)3072 * 768);
        cvt_bf16<<<cgrid((long)768 * 3072), blk, 0, stream>>>(mlp_w2 + (size_t)l * 768 * 3072, wl + off_w2, (long)768 * 3072);

        ln_mod<<<M, blk, 0, stream>>>(x, norm1_w + (size_t)l * D, adaL + D, adaL, 6 * D, xm);
        gemm_mfma<0, 1><<<dim3(2304 / 128, M / 128), blk, 0, stream>>>(
            xm, wl + off_qkvw, nullptr, qkvb, M, 2304, 768);
        repack_vt<<<dim3(16, 24), blk, 0, stream>>>(qkvb, vtb);
        attn_mfma<<<dim3(16, 24), blk, 0, stream>>>(qkvb, vtb, aob);
        gemm_mfma<0, 0><<<dim3(768 / 128, M / 128), blk, 0, stream>>>(
            aob, wl + off_outw, nullptr, yb, M, 768, 768);
        resid_gate<<<(M * D) / 256, blk, 0, stream>>>(x, yb, adaL + 2 * D, 6 * D);

        ln_mod<<<M, blk, 0, stream>>>(x, norm2_w + (size_t)l * D, adaL + 4 * D, adaL + 3 * D, 6 * D, xm);
        gemm_mfma<1, 1><<<dim3(3072 / 128, M / 128), blk, 0, stream>>>(
            xm, wl + off_w1, mlp_b1 + (size_t)l * MLP, hbb, M, 3072, 768);
        gemm_mfma<0, 0><<<dim3(768 / 128, M / 128), blk, 0, stream>>>(
            hbb, wl + off_w2, mlp_b2 + (size_t)l * D, yb, M, 768, 3072);
        resid_gate<<<(M * D) / 256, blk, 0, stream>>>(x, yb, adaL + 5 * D, 6 * D);
    }

    // final
    ln_mod<<<M, blk, 0, stream>>>(x, normf_w, adaf + D, adaf, 2 * D, xm);
    gemm_mfma<0, 0><<<dim3((V + 127) / 128, M / 128), blk, 0, stream>>>(
        xm, linb, lin_b, (float*)d_out, M, V, 768);
}